// Round 1
// baseline (467.888 us; speedup 1.0000x reference)
//
#include <hip/hip_runtime.h>

#define DD 4096
#define MM 1024
#define LL 8192

// ---------------------------------------------------------------------------
// y[row] = dot(A[row, :], x)   A is [grid, NCOLS] row-major, NCOLS % 1024 == 0
// block = 256 threads, one row per block, float4 loads.
// ---------------------------------------------------------------------------
template <int NCOLS>
__global__ __launch_bounds__(256) void gemv_rows(const float* __restrict__ A,
                                                 const float* __restrict__ x,
                                                 float* __restrict__ y) {
    const int row = blockIdx.x;
    const float4* Arow = reinterpret_cast<const float4*>(A + (size_t)row * NCOLS);
    const float4* x4 = reinterpret_cast<const float4*>(x);
    float acc = 0.f;
#pragma unroll
    for (int k = threadIdx.x; k < NCOLS / 4; k += 256) {
        float4 a = Arow[k];
        float4 b = x4[k];
        acc += a.x * b.x + a.y * b.y + a.z * b.z + a.w * b.w;
    }
#pragma unroll
    for (int off = 32; off; off >>= 1) acc += __shfl_down(acc, off, 64);
    __shared__ float sh[4];
    const int wave = threadIdx.x >> 6, lane = threadIdx.x & 63;
    if (lane == 0) sh[wave] = acc;
    __syncthreads();
    if (threadIdx.x == 0) y[row] = sh[0] + sh[1] + sh[2] + sh[3];
}

// ---------------------------------------------------------------------------
// v[row] = prelu(bias[row] + dot(A[row,:], x), a[0])    NCOLS = 4096
// ---------------------------------------------------------------------------
__global__ __launch_bounds__(256) void gemv_prelu(const float* __restrict__ A,
                                                  const float* __restrict__ x,
                                                  const float* __restrict__ bias,
                                                  const float* __restrict__ a,
                                                  float* __restrict__ y) {
    const int row = blockIdx.x;
    const float4* Arow = reinterpret_cast<const float4*>(A + (size_t)row * DD);
    const float4* x4 = reinterpret_cast<const float4*>(x);
    float acc = 0.f;
#pragma unroll
    for (int k = threadIdx.x; k < DD / 4; k += 256) {
        float4 a4 = Arow[k];
        float4 b4 = x4[k];
        acc += a4.x * b4.x + a4.y * b4.y + a4.z * b4.z + a4.w * b4.w;
    }
#pragma unroll
    for (int off = 32; off; off >>= 1) acc += __shfl_down(acc, off, 64);
    __shared__ float sh[4];
    const int wave = threadIdx.x >> 6, lane = threadIdx.x & 63;
    if (lane == 0) sh[wave] = acc;
    __syncthreads();
    if (threadIdx.x == 0) {
        float t = bias[row] + sh[0] + sh[1] + sh[2] + sh[3];
        y[row] = (t >= 0.f) ? t : a[0] * t;
    }
}

// ---------------------------------------------------------------------------
// Column pass over memory_nodes [DD, MM] row-major:
//   zacc[m]  += sum_{r in chunk} s_q[r] * mem[r, m]
//   sqacc[m] += sum_{r in chunk} mem[r, m]^2
// grid = (MM/256, DD/ROWS); consecutive threads read consecutive m (coalesced).
// ---------------------------------------------------------------------------
__global__ __launch_bounds__(256) void col_accum(const float* __restrict__ mem,
                                                 const float* __restrict__ sq,
                                                 float* __restrict__ zacc,
                                                 float* __restrict__ sqacc) {
    const int ROWS = 64;
    const int m = blockIdx.x * 256 + threadIdx.x;
    const int r0 = blockIdx.y * ROWS;
    float z = 0.f, s = 0.f;
#pragma unroll 4
    for (int r = 0; r < ROWS; ++r) {
        float w = sq[r0 + r];               // wave-uniform broadcast
        float v = mem[(size_t)(r0 + r) * MM + m];
        z += w * v;
        s += v * v;
    }
    atomicAdd(&zacc[m], z);
    atomicAdd(&sqacc[m], s);
}

// ---------------------------------------------------------------------------
// Softmax over M=1024 with folded column-norm:
//   t[m] = zacc[m] / sqrt(sqacc[m]);  p = softmax(t);  qout[m] = p[m]/sqrt(sqacc[m])
// single block of 1024 threads (16 waves)
// ---------------------------------------------------------------------------
__global__ __launch_bounds__(1024) void softmax_fold(const float* __restrict__ zacc,
                                                     const float* __restrict__ sqacc,
                                                     float* __restrict__ qout) {
    __shared__ float sh[16];
    __shared__ float red[2];
    const int m = threadIdx.x;
    const int wave = m >> 6, lane = m & 63;
    const float rn = rsqrtf(fmaxf(sqacc[m], 1e-24f));  // 1/||memory[:,m]||
    const float t = zacc[m] * rn;
    float mx = t;
#pragma unroll
    for (int off = 32; off; off >>= 1) mx = fmaxf(mx, __shfl_down(mx, off, 64));
    if (lane == 0) sh[wave] = mx;
    __syncthreads();
    if (m == 0) {
        float v = sh[0];
        for (int i = 1; i < 16; ++i) v = fmaxf(v, sh[i]);
        red[0] = v;
    }
    __syncthreads();
    const float e = __expf(t - red[0]);
    float s = e;
#pragma unroll
    for (int off = 32; off; off >>= 1) s += __shfl_down(s, off, 64);
    if (lane == 0) sh[wave] = s;
    __syncthreads();
    if (m == 0) {
        float v = 0.f;
        for (int i = 0; i < 16; ++i) v += sh[i];
        red[1] = v;
    }
    __syncthreads();
    qout[m] = (e / red[1]) * rn;
}

extern "C" void kernel_launch(void* const* d_in, const int* in_sizes, int n_in,
                              void* d_out, int out_size, void* d_ws, size_t ws_size,
                              hipStream_t stream) {
    // inputs: 0 input, 1 query, 2 F_i, 3 F_q, 4 keys, 5 memory_nodes,
    //         6 U, 7 V, 8 W, 9 R, 10 H, 11 a_mem, 12 a_out
    const float* query = (const float*)d_in[1];
    const float* F_q   = (const float*)d_in[3];
    const float* mem   = (const float*)d_in[5];
    const float* R     = (const float*)d_in[9];
    const float* H     = (const float*)d_in[10];
    const float* a_out = (const float*)d_in[12];
    float* out = (float*)d_out;

    // workspace layout (floats)
    float* ws    = (float*)d_ws;
    float* s_q   = ws;            // [4096]
    float* zacc  = ws + 4096;     // [1024]
    float* sqacc = ws + 5120;     // [1024]
    float* qv    = ws + 6144;     // [1024]
    float* u     = ws + 7168;     // [4096]
    float* v     = ws + 11264;    // [4096]

    // s_q = F_q @ query
    gemv_rows<LL><<<DD, 256, 0, stream>>>(F_q, query, s_q);

    // zero the accumulators (ws is poisoned 0xAA before every launch)
    hipMemsetAsync(zacc, 0, 2048 * sizeof(float), stream);

    // column dot + column sumsq over memory_nodes
    dim3 gcol(MM / 256, DD / 64);
    col_accum<<<gcol, 256, 0, stream>>>(mem, s_q, zacc, sqacc);

    // softmax + fold 1/norm -> qv
    softmax_fold<<<1, 1024, 0, stream>>>(zacc, sqacc, qv);

    // u = memory_nodes @ qv
    gemv_rows<MM><<<DD, 256, 0, stream>>>(mem, qv, u);

    // v = prelu(s_q + H @ u, a_out)
    gemv_prelu<<<DD, 256, 0, stream>>>(H, u, s_q, a_out, v);

    // y = R @ v
    gemv_rows<DD><<<DD, 256, 0, stream>>>(R, v, out);
}